// Round 9
// baseline (316.222 us; speedup 1.0000x reference)
//
#include <hip/hip_runtime.h>
#include <hip/hip_bf16.h>

typedef unsigned short ushort;
typedef __attribute__((ext_vector_type(8))) short bf16x8;
typedef __attribute__((ext_vector_type(4))) float f32x4;
typedef __attribute__((ext_vector_type(4))) unsigned short ushort4v;

#define BSZ  4
#define LSEQ 1024
#define CIN  512
#define C2   1024
#define NH   8
#define GEPS 1e-4f

static __device__ __forceinline__ ushort f2b(float f) {
    __hip_bfloat16 h = __float2bfloat16(f);
    return *reinterpret_cast<ushort*>(&h);
}
static __device__ __forceinline__ float b2f(ushort u) {
    __hip_bfloat16 h = *reinterpret_cast<__hip_bfloat16*>(&u);
    return __bfloat162float(h);
}

// ---------------- P1: split x into hi/lo bf16 ----------------
__global__ __launch_bounds__(256) void prep_xsplit(const float* __restrict__ x,
                                                   ushort* __restrict__ xh,
                                                   ushort* __restrict__ xl) {
    const size_t i4 = (size_t)blockIdx.x * 256 + threadIdx.x;
    const float4 v = *reinterpret_cast<const float4*>(&x[i4 * 4]);
    ushort4v h, lo;
    const float vv[4] = {v.x, v.y, v.z, v.w};
    #pragma unroll
    for (int c = 0; c < 4; ++c) {
        const ushort hh = f2b(vv[c]);
        h[c] = hh;
        lo[c] = f2b(vv[c] - b2f(hh));
    }
    *reinterpret_cast<ushort4v*>(&xh[i4 * 4]) = h;
    *reinterpret_cast<ushort4v*>(&xl[i4 * 4]) = lo;
}

// ---------------- P2: W [512][1024] -> WT hi/lo bf16 [1024][512] ----------------
__global__ __launch_bounds__(256) void prep_wT(const float* __restrict__ W,
                                               ushort* __restrict__ wth,
                                               ushort* __restrict__ wtl) {
    __shared__ float tl[64][65];
    const int k0 = blockIdx.y * 64, n0 = blockIdx.x * 64;
    const int t = threadIdx.x;
    #pragma unroll
    for (int u = 0; u < 16; ++u) {
        const int idx = t + 256 * u;
        const int kk = idx >> 6, nn = idx & 63;
        tl[kk][nn] = W[(size_t)(k0 + kk) * 1024 + n0 + nn];
    }
    __syncthreads();
    #pragma unroll
    for (int u = 0; u < 16; ++u) {
        const int idx = t + 256 * u;
        const int nn = idx >> 6, kk = idx & 63;
        const float v = tl[kk][nn];
        const ushort h = f2b(v);
        wth[(size_t)(n0 + nn) * 512 + k0 + kk] = h;
        wtl[(size_t)(n0 + nn) * 512 + k0 + kk] = f2b(v - b2f(h));
    }
}

// ---------------- P3: fused rel tables ----------------
__global__ __launch_bounds__(256) void prep_rel(const float* __restrict__ rel,
                                                ushort* __restrict__ relT,
                                                ushort* __restrict__ relV) {
    const int t = threadIdx.x;
    if (blockIdx.x < 32) {
        __shared__ float tl[64][65];
        const int r0 = blockIdx.x * 64;
        #pragma unroll
        for (int u = 0; u < 16; ++u) {
            const int idx = t + 256 * u;
            const int dd = idx >> 6, rr = idx & 63;
            int r = r0 + rr; if (r > 2046) r = 2046;
            tl[dd][rr] = rel[(size_t)(dd ^ 32) * 2047 + r];
        }
        __syncthreads();
        #pragma unroll
        for (int u = 0; u < 16; ++u) {
            const int idx = t + 256 * u;
            const int rr = idx >> 6, dd = idx & 63;
            relT[(size_t)(r0 + rr) * 64 + dd] = f2b(tl[dd][rr]);
        }
    } else {
        const int idx = (blockIdx.x - 32) * 256 + t;   // 64*2048
        const int dv = idx >> 11, r = idx & 2047;
        const int rc = r > 2046 ? 2046 : r;
        relV[(size_t)dv * 2048 + r] = f2b(rel[(size_t)(64 + dv) * 2047 + rc]);
    }
}

// ---------------- K1: qkv = x @ W, split-bf16 MFMA, 128x64 tiles, fused GN stats ----------------
__global__ __launch_bounds__(256) void gemm_qkv_mfma(const ushort* __restrict__ xh,
                                                     const ushort* __restrict__ xl,
                                                     const ushort* __restrict__ wth,
                                                     const ushort* __restrict__ wtl,
                                                     float* __restrict__ qkv,
                                                     float* __restrict__ sumq) {
    __shared__ ushort Ah[128][40];
    __shared__ ushort Al[128][40];
    __shared__ ushort Bh[64][40];
    __shared__ ushort Bl[64][40];
    const int t = threadIdx.x;
    const int w = t >> 6, l = t & 63;
    const int lr = l & 15, lq = l >> 4;
    const int m0 = blockIdx.y * 128, n0 = blockIdx.x * 64;
    const int b = m0 >> 10;
    f32x4 acc[2][4] = {};
    for (int k0 = 0; k0 < 512; k0 += 32) {
        __syncthreads();
        #pragma unroll
        for (int u = 0; u < 2; ++u) {
            const int idx = t + 256 * u;
            const int r = idx >> 2, c16 = (idx & 3) * 8;
            *(bf16x8*)&Ah[r][c16] = *(const bf16x8*)&xh[(size_t)(m0 + r) * 512 + k0 + c16];
            *(bf16x8*)&Al[r][c16] = *(const bf16x8*)&xl[(size_t)(m0 + r) * 512 + k0 + c16];
        }
        {
            const int r = t >> 2, c16 = (t & 3) * 8;
            *(bf16x8*)&Bh[r][c16] = *(const bf16x8*)&wth[(size_t)(n0 + r) * 512 + k0 + c16];
            *(bf16x8*)&Bl[r][c16] = *(const bf16x8*)&wtl[(size_t)(n0 + r) * 512 + k0 + c16];
        }
        __syncthreads();
        bf16x8 ah[2], av[2];
        #pragma unroll
        for (int mi = 0; mi < 2; ++mi) {
            ah[mi] = *(const bf16x8*)&Ah[32 * w + 16 * mi + lr][8 * lq];
            av[mi] = *(const bf16x8*)&Al[32 * w + 16 * mi + lr][8 * lq];
        }
        #pragma unroll
        for (int ni = 0; ni < 4; ++ni) {
            const bf16x8 bh = *(const bf16x8*)&Bh[16 * ni + lr][8 * lq];
            const bf16x8 bl = *(const bf16x8*)&Bl[16 * ni + lr][8 * lq];
            #pragma unroll
            for (int mi = 0; mi < 2; ++mi) {
                f32x4 a = acc[mi][ni];
                a = __builtin_amdgcn_mfma_f32_16x16x32_bf16(ah[mi], bl, a, 0, 0, 0);
                a = __builtin_amdgcn_mfma_f32_16x16x32_bf16(av[mi], bh, a, 0, 0, 0);
                a = __builtin_amdgcn_mfma_f32_16x16x32_bf16(ah[mi], bh, a, 0, 0, 0);
                acc[mi][ni] = a;
            }
        }
    }
    #pragma unroll
    for (int mi = 0; mi < 2; ++mi)
        #pragma unroll
        for (int ni = 0; ni < 4; ++ni)
            #pragma unroll
            for (int e = 0; e < 4; ++e)
                qkv[(size_t)(m0 + 32 * w + 16 * mi + 4 * lq + e) * 1024 + n0 + 16 * ni + lr] = acc[mi][ni][e];
    #pragma unroll
    for (int ni = 0; ni < 4; ++ni) {
        float s = 0.f, s2 = 0.f;
        #pragma unroll
        for (int mi = 0; mi < 2; ++mi)
            #pragma unroll
            for (int e = 0; e < 4; ++e) { const float v = acc[mi][ni][e]; s += v; s2 += v * v; }
        #pragma unroll
        for (int o = 32; o; o >>= 1) { s += __shfl_xor(s, o, 64); s2 += __shfl_xor(s2, o, 64); }
        if (l == 0) {
            const int g = (n0 + 16 * ni) >> 5;
            atomicAdd(&sumq[(b * 32 + g) * 2 + 0], s);
            atomicAdd(&sumq[(b * 32 + g) * 2 + 1], s2);
        }
    }
}

// ---------------- K2: apply qkv GN (inline finalize) -> bf16 qg + lo (q/k) + transposed v ----------------
__global__ __launch_bounds__(256) void gn_apply_bf(const float* __restrict__ qkv,
                                                   const float* __restrict__ sumq,
                                                   const float* __restrict__ scale,
                                                   const float* __restrict__ bias,
                                                   ushort* __restrict__ qg,
                                                   ushort* __restrict__ qlo,
                                                   ushort* __restrict__ vb) {
    __shared__ float tile[64][65];
    const int b  = blockIdx.z;
    const int l0 = blockIdx.y * 64, c0 = blockIdx.x * 64;
    const int t  = threadIdx.x;
    const bool vhalf = (c0 & 64);
    const int h = c0 >> 7;
    #pragma unroll
    for (int u = 0; u < 16; ++u) {
        const int idx = t + 256 * u;
        const int lr = idx >> 6, cr = idx & 63;
        const int c = c0 + cr, g = c >> 5;
        const float s  = sumq[(b * 32 + g) * 2 + 0];
        const float s2 = sumq[(b * 32 + g) * 2 + 1];
        const float mu = s * (1.f / 32768.f);
        const float rr = rsqrtf(fmaxf(s2 * (1.f / 32768.f) - mu * mu, 0.f) + GEPS);
        float v = qkv[(size_t)(b * LSEQ + l0 + lr) * C2 + c];
        v = (v - mu) * rr * scale[c] + bias[c];
        const ushort hi = f2b(v);
        qg[(size_t)(b * LSEQ + l0 + lr) * C2 + c] = hi;
        if (vhalf) tile[lr][cr] = v;
        else qlo[(size_t)(b * LSEQ + l0 + lr) * 512 + h * 64 + cr] = f2b(v - b2f(hi));
    }
    if (vhalf) {
        __syncthreads();
        #pragma unroll
        for (int u = 0; u < 16; ++u) {
            const int idx = t + 256 * u;
            const int cw = idx >> 6, lw = idx & 63;   // cw = dv
            vb[((size_t)((b * NH + h) * 64 + cw)) * LSEQ + l0 + lw] = f2b(tile[lw][cw]);
        }
    }
}

// ---------------- K3: MFMA flash attention — j-split waves, barrier-free loop ----------------
// Wave = (strip of 16 i-rows, half of j-range). All MFMA B-operands direct from global (L2-hot).
// LDS: wave-private scratch only: per wave [16][264] ushorts = TU [0,88) | Ps [88,160) | Pr [160,264).
// End: partner waves (same strip, jh 0/1) merge partial (m,l,O) via LDS + one barrier.
// mfma_f32_16x16x32_bf16: A[m][k],B[n][k] k-contig; lane(lq=l>>4,lr=l&15) reads row lr, k 8lq..;
// C/D: col=lr, row=4lq+e.
__global__ __launch_bounds__(256, 4) void attn_mfma(const ushort* __restrict__ qg,
                                                    const ushort* __restrict__ qlo,
                                                    const ushort* __restrict__ vbuf,
                                                    const ushort* __restrict__ relT,
                                                    const ushort* __restrict__ relV,
                                                    float* __restrict__ aout,
                                                    float* __restrict__ sumo) {
    __shared__ __align__(16) ushort wscr[4][16][264];

    const int t = threadIdx.x;
    const int w = t >> 6, l = t & 63;
    const int lr = l & 15, lq = l >> 4;
    const int h = blockIdx.y, b = blockIdx.z;
    const int i0s = blockIdx.x * 32 + (w >> 1) * 16;   // this wave's 16-row strip
    const int jh = w & 1;                              // j-half

    // zero Pr region [160,264)
    for (int idx = l; idx < 16 * 52; idx += 64) {
        const int row = idx / 52, c = idx % 52;
        *(unsigned int*)&wscr[w][row][160 + 2 * c] = 0;
    }

    // A fragments (persistent)
    const size_t arow = (size_t)(b * LSEQ + i0s + lr);
    const bf16x8 a_q  = *(const bf16x8*)&qg[arow * C2 + h * 128 + 8 * lq];
    const bf16x8 a_k  = *(const bf16x8*)&qg[arow * C2 + h * 128 + 32 + 8 * lq];
    const bf16x8 a_ql = *(const bf16x8*)&qlo[arow * 512 + h * 64 + 8 * lq];

    float m_r[4], l_r[4];
    #pragma unroll
    for (int e = 0; e < 4; ++e) { m_r[e] = -3.0e38f; l_r[e] = 0.f; }
    f32x4 Oa[4] = {};

    const int tb = 4 * lq + 63 - lr;
    const size_t vrow0 = (size_t)((b * NH + h) * 64);

    for (int it = 0; it < 8; ++it) {
        const int j0 = jh * 512 + it * 64;
        const int r0 = i0s - j0 + 960;     // multiple of 16 -> 16B-aligned reads

        // ---- TU band: 5 tiles, B direct from relT ----
        #pragma unroll
        for (int ct = 0; ct < 5; ++ct) {
            const size_t rr = (size_t)(r0 + 16 * ct + lr) * 64;
            f32x4 acc = {0.f, 0.f, 0.f, 0.f};
            acc = __builtin_amdgcn_mfma_f32_16x16x32_bf16(a_q, *(const bf16x8*)&relT[rr + 8 * lq], acc, 0, 0, 0);
            acc = __builtin_amdgcn_mfma_f32_16x16x32_bf16(a_k, *(const bf16x8*)&relT[rr + 32 + 8 * lq], acc, 0, 0, 0);
            #pragma unroll
            for (int e = 0; e < 4; ++e) wscr[w][4 * lq + e][16 * ct + lr] = f2b(acc[e]);
        }

        // ---- S1 (compensated bf16, k direct from global) + TU skew-gather ----
        f32x4 sv[4];
        #pragma unroll
        for (int n = 0; n < 4; ++n) {
            const size_t krow = (size_t)(b * LSEQ + j0 + 16 * n + lr);
            const bf16x8 b_hi = *(const bf16x8*)&qg[krow * C2 + h * 128 + 32 + 8 * lq];
            const bf16x8 b_lo = *(const bf16x8*)&qlo[krow * 512 + h * 64 + 32 + 8 * lq];
            f32x4 acc = {0.f, 0.f, 0.f, 0.f};
            acc = __builtin_amdgcn_mfma_f32_16x16x32_bf16(a_q,  b_lo, acc, 0, 0, 0);
            acc = __builtin_amdgcn_mfma_f32_16x16x32_bf16(a_ql, b_hi, acc, 0, 0, 0);
            acc = __builtin_amdgcn_mfma_f32_16x16x32_bf16(a_q,  b_hi, acc, 0, 0, 0);
            #pragma unroll
            for (int e = 0; e < 4; ++e) acc[e] += b2f(wscr[w][4 * lq + e][tb + e - 16 * n]);
            sv[n] = acc;
        }

        // ---- in-wave online softmax ----
        float mx[4];
        #pragma unroll
        for (int e = 0; e < 4; ++e)
            mx[e] = fmaxf(fmaxf(sv[0][e], sv[1][e]), fmaxf(sv[2][e], sv[3][e]));
        #pragma unroll
        for (int o = 1; o < 16; o <<= 1)
            #pragma unroll
            for (int e = 0; e < 4; ++e) mx[e] = fmaxf(mx[e], __shfl_xor(mx[e], o, 64));
        float alpha[4], ssum[4];
        #pragma unroll
        for (int e = 0; e < 4; ++e) {
            const float mn = fmaxf(m_r[e], mx[e]);
            alpha[e] = __expf(m_r[e] - mn);
            m_r[e] = mn;
            ssum[e] = 0.f;
        }
        #pragma unroll
        for (int n = 0; n < 4; ++n)
            #pragma unroll
            for (int e = 0; e < 4; ++e) {
                const float p = __expf(sv[n][e] - m_r[e]);
                ssum[e] += p;
                const ushort pb = f2b(p);
                wscr[w][4 * lq + e][88 + 16 * n + lr] = pb;          // Ps
                wscr[w][4 * lq + e][160 + tb + e - 16 * n] = pb;     // Pr (band [0,78])
            }
        #pragma unroll
        for (int o = 1; o < 16; o <<= 1)
            #pragma unroll
            for (int e = 0; e < 4; ++e) ssum[e] += __shfl_xor(ssum[e], o, 64);
        #pragma unroll
        for (int e = 0; e < 4; ++e) l_r[e] = l_r[e] * alpha[e] + ssum[e];

        // ---- PV: O = diag(alpha)*O + P*v + Pr*rV (v, rV direct from global) ----
        const bf16x8 pa0 = *(const bf16x8*)&wscr[w][lr][88 + 8 * lq];
        const bf16x8 pa1 = *(const bf16x8*)&wscr[w][lr][88 + 32 + 8 * lq];
        bf16x8 pra[3];
        #pragma unroll
        for (int kk = 0; kk < 3; ++kk) pra[kk] = *(const bf16x8*)&wscr[w][lr][160 + 32 * kk + 8 * lq];
        #pragma unroll
        for (int n = 0; n < 4; ++n) {
            const size_t vr = (vrow0 + 16 * n + lr) * LSEQ;
            const size_t rvr = (size_t)(16 * n + lr) * 2048 + r0;
            f32x4 acc = Oa[n];
            #pragma unroll
            for (int e = 0; e < 4; ++e) acc[e] *= alpha[e];
            acc = __builtin_amdgcn_mfma_f32_16x16x32_bf16(pa0, *(const bf16x8*)&vbuf[vr + j0 + 8 * lq], acc, 0, 0, 0);
            acc = __builtin_amdgcn_mfma_f32_16x16x32_bf16(pa1, *(const bf16x8*)&vbuf[vr + j0 + 32 + 8 * lq], acc, 0, 0, 0);
            #pragma unroll
            for (int kk = 0; kk < 3; ++kk) {
                acc = __builtin_amdgcn_mfma_f32_16x16x32_bf16(pra[kk], *(const bf16x8*)&relV[rvr + 32 * kk + 8 * lq], acc, 0, 0, 0);
            }
            Oa[n] = acc;
        }
    }

    // ---- merge j-halves (partner waves w, w^1) ----
    float* fs = (float*)&wscr[w][0][0];     // 24 f32/lane <= 8448 B
    #pragma unroll
    for (int n = 0; n < 4; ++n)
        #pragma unroll
        for (int e = 0; e < 4; ++e) fs[(4 * n + e) * 64 + l] = Oa[n][e];
    #pragma unroll
    for (int e = 0; e < 4; ++e) { fs[(16 + e) * 64 + l] = m_r[e]; fs[(20 + e) * 64 + l] = l_r[e]; }
    __syncthreads();
    if (jh == 0) {
        const float* fp = (const float*)&wscr[w + 1][0][0];
        float a0[4], a1[4], Li[4];
        #pragma unroll
        for (int e = 0; e < 4; ++e) {
            const float m1 = fp[(16 + e) * 64 + l], l1 = fp[(20 + e) * 64 + l];
            const float mn = fmaxf(m_r[e], m1);
            a0[e] = __expf(m_r[e] - mn);
            a1[e] = __expf(m1 - mn);
            Li[e] = 1.f / (l_r[e] * a0[e] + l1 * a1[e]);
        }
        #pragma unroll
        for (int n = 0; n < 4; ++n) {
            float s = 0.f, s2 = 0.f;
            #pragma unroll
            for (int e = 0; e < 4; ++e) {
                const float o = (Oa[n][e] * a0[e] + fp[(4 * n + e) * 64 + l] * a1[e]) * Li[e];
                aout[(size_t)(b * LSEQ + i0s + 4 * lq + e) * CIN + h * 64 + 16 * n + lr] = o;
                s += o; s2 += o * o;
            }
            #pragma unroll
            for (int o = 32; o; o >>= 1) { s += __shfl_xor(s, o, 64); s2 += __shfl_xor(s2, o, 64); }
            if (l == 0) {
                atomicAdd(&sumo[(b * 32 + h * 4 + n) * 2 + 0], s);
                atomicAdd(&sumo[(b * 32 + h * 4 + n) * 2 + 1], s2);
            }
        }
    }
}

// ---------------- K4: apply output GN (inline finalize) ----------------
__global__ __launch_bounds__(256) void gn_out_apply(const float* __restrict__ aout,
                                                    const float* __restrict__ sumo,
                                                    const float* __restrict__ scale,
                                                    const float* __restrict__ bias,
                                                    float* __restrict__ out) {
    const int idx4 = blockIdx.x * 256 + threadIdx.x;
    const int c = (idx4 & 127) * 4;
    const size_t row = idx4 >> 7;
    const int b = (int)(row >> 10);
    const int g = c >> 4;
    const float s  = sumo[(b * 32 + g) * 2 + 0];
    const float s2 = sumo[(b * 32 + g) * 2 + 1];
    const float mu = s * (1.f / 16384.f);
    const float rr = rsqrtf(fmaxf(s2 * (1.f / 16384.f) - mu * mu, 0.f) + GEPS);
    const float4 v = *reinterpret_cast<const float4*>(&aout[row * 512 + c]);
    const float4 sc = *reinterpret_cast<const float4*>(&scale[c]);
    const float4 bi = *reinterpret_cast<const float4*>(&bias[c]);
    float4 o;
    o.x = (v.x - mu) * rr * sc.x + bi.x;
    o.y = (v.y - mu) * rr * sc.y + bi.y;
    o.z = (v.z - mu) * rr * sc.z + bi.z;
    o.w = (v.w - mu) * rr * sc.w + bi.w;
    *reinterpret_cast<float4*>(&out[row * 512 + c]) = o;
}

extern "C" void kernel_launch(void* const* d_in, const int* in_sizes, int n_in,
                              void* d_out, int out_size, void* d_ws, size_t ws_size,
                              hipStream_t stream) {
    (void)in_sizes; (void)n_in; (void)out_size; (void)ws_size;
    const float* x   = (const float*)d_in[0];
    const float* W   = (const float*)d_in[1];
    const float* gqs = (const float*)d_in[2];
    const float* gqb = (const float*)d_in[3];
    const float* rel = (const float*)d_in[4];
    const float* gos = (const float*)d_in[5];
    const float* gob = (const float*)d_in[6];
    float* out = (float*)d_out;

    char* ws = (char*)d_ws;
    float*  qkv  = (float*)ws;                                  // 16 MB [b][l][c2] f32
    ushort* qg   = (ushort*)(ws + (16u << 20));                 //  8 MB [b][l][c2] bf16
    ushort* vb   = (ushort*)(ws + (24u << 20));                 //  4 MB [b][h][dv][l]
    ushort* rTb  = (ushort*)(ws + (28u << 20));                 // 256 KB
    ushort* rVb  = (ushort*)(ws + (28u << 20) + (256u << 10));  // 256 KB
    ushort* qlo  = (ushort*)(ws + (28u << 20) + (512u << 10));  //  4 MB [b][l][h*64]
    float*  aout = (float*)ws;                                  // reuse qkv region
    float*  stats = (float*)(ws + (32u << 20) + (512u << 10));  // 2 KB
    float* sumq = stats;          // [b][g][2] raw sums (qkv GN)
    float* sumo = stats + 256;    // [b][g][2] raw sums (out GN)
    // transient (dead after gemm): alias qg/vb regions
    ushort* xhi = (ushort*)(ws + (16u << 20));                  // 4 MB
    ushort* xlo = (ushort*)(ws + (20u << 20));                  // 4 MB
    ushort* wth = (ushort*)(ws + (24u << 20));                  // 1 MB
    ushort* wtl = (ushort*)(ws + (25u << 20));                  // 1 MB

    hipMemsetAsync(stats, 0, 2048, stream);
    prep_xsplit<<<2048, 256, 0, stream>>>(x, xhi, xlo);
    prep_wT<<<dim3(16, 8), 256, 0, stream>>>(W, wth, wtl);
    prep_rel<<<544, 256, 0, stream>>>(rel, rTb, rVb);
    gemm_qkv_mfma<<<dim3(16, 32), 256, 0, stream>>>(xhi, xlo, wth, wtl, qkv, sumq);
    gn_apply_bf<<<dim3(16, 16, BSZ), 256, 0, stream>>>(qkv, sumq, gqs, gqb, qg, qlo, vb);
    attn_mfma<<<dim3(32, NH, BSZ), 256, 0, stream>>>(qg, qlo, vb, rTb, rVb, aout, sumo);
    gn_out_apply<<<2048, 256, 0, stream>>>(aout, sumo, gos, gob, out);
}

// Round 10
// 230.596 us; speedup vs baseline: 1.3713x; 1.3713x over previous
//
#include <hip/hip_runtime.h>
#include <hip/hip_bf16.h>

typedef unsigned short ushort;
typedef unsigned int uint;
typedef __attribute__((ext_vector_type(8))) short bf16x8;
typedef __attribute__((ext_vector_type(4))) float f32x4;
typedef __attribute__((ext_vector_type(4))) unsigned short ushort4v;

#define BSZ  4
#define LSEQ 1024
#define CIN  512
#define C2   1024
#define NH   8
#define GEPS 1e-4f

static __device__ __forceinline__ ushort f2b(float f) {
    __hip_bfloat16 h = __float2bfloat16(f);
    return *reinterpret_cast<ushort*>(&h);
}
static __device__ __forceinline__ float b2f(ushort u) {
    __hip_bfloat16 h = *reinterpret_cast<__hip_bfloat16*>(&u);
    return __bfloat162float(h);
}

// async global->LDS, 16B per lane; LDS dest = wave-uniform base + lane*16, SRC per-lane.
static __device__ __forceinline__ void gl16(const void* g, void* l) {
    __builtin_amdgcn_global_load_lds((const __attribute__((address_space(1))) void*)g,
                                     (__attribute__((address_space(3))) void*)l, 16, 0, 0);
}

// ---------------- P: fused preps: xsplit | wT split | rel tables ----------------
__global__ __launch_bounds__(256) void prep_all(const float* __restrict__ x,
                                                const float* __restrict__ W,
                                                const float* __restrict__ rel,
                                                ushort* __restrict__ xh,
                                                ushort* __restrict__ xl,
                                                ushort* __restrict__ wth,
                                                ushort* __restrict__ wtl,
                                                ushort* __restrict__ relT,
                                                ushort* __restrict__ relV) {
    __shared__ float tl[64][65];
    const int t = threadIdx.x;
    const int bid = blockIdx.x;
    if (bid < 2048) {
        const size_t i4 = (size_t)bid * 256 + t;
        const float4 v = *reinterpret_cast<const float4*>(&x[i4 * 4]);
        ushort4v h, lo;
        const float vv[4] = {v.x, v.y, v.z, v.w};
        #pragma unroll
        for (int c = 0; c < 4; ++c) {
            const ushort hh = f2b(vv[c]);
            h[c] = hh;
            lo[c] = f2b(vv[c] - b2f(hh));
        }
        *reinterpret_cast<ushort4v*>(&xh[i4 * 4]) = h;
        *reinterpret_cast<ushort4v*>(&xl[i4 * 4]) = lo;
    } else if (bid < 2176) {
        const int bb = bid - 2048;
        const int k0 = (bb >> 4) * 64, n0 = (bb & 15) * 64;
        #pragma unroll
        for (int u = 0; u < 16; ++u) {
            const int idx = t + 256 * u;
            const int kk = idx >> 6, nn = idx & 63;
            tl[kk][nn] = W[(size_t)(k0 + kk) * 1024 + n0 + nn];
        }
        __syncthreads();
        #pragma unroll
        for (int u = 0; u < 16; ++u) {
            const int idx = t + 256 * u;
            const int nn = idx >> 6, kk = idx & 63;
            const float v = tl[kk][nn];
            const ushort h = f2b(v);
            wth[(size_t)(n0 + nn) * 512 + k0 + kk] = h;
            wtl[(size_t)(n0 + nn) * 512 + k0 + kk] = f2b(v - b2f(h));
        }
    } else {
        const int bb = bid - 2176;
        if (bb < 32) {
            const int r0 = bb * 64;
            #pragma unroll
            for (int u = 0; u < 16; ++u) {
                const int idx = t + 256 * u;
                const int dd = idx >> 6, rr = idx & 63;
                int r = r0 + rr; if (r > 2046) r = 2046;
                tl[dd][rr] = rel[(size_t)(dd ^ 32) * 2047 + r];
            }
            __syncthreads();
            #pragma unroll
            for (int u = 0; u < 16; ++u) {
                const int idx = t + 256 * u;
                const int rr = idx >> 6, dd = idx & 63;
                relT[(size_t)(r0 + rr) * 64 + dd] = f2b(tl[dd][rr]);
            }
        } else {
            const int idx = (bb - 32) * 256 + t;   // 64*2048
            const int dv = idx >> 11, r = idx & 2047;
            const int rc = r > 2046 ? 2046 : r;
            relV[(size_t)dv * 2048 + r] = f2b(rel[(size_t)(64 + dv) * 2047 + rc]);
        }
    }
}

// ---------------- K1: qkv = x @ W, split-bf16 MFMA, gload_lds staging, fused GN stats ----------------
// LDS linear rows (32 ushort = 64B); swizzle: phys_byte_col = logical ^ ((row&3)<<4).
__global__ __launch_bounds__(256) void gemm_qkv_mfma(const ushort* __restrict__ xh,
                                                     const ushort* __restrict__ xl,
                                                     const ushort* __restrict__ wth,
                                                     const ushort* __restrict__ wtl,
                                                     float* __restrict__ qkv,
                                                     float* __restrict__ sumq) {
    __shared__ ushort Ah[128][32];
    __shared__ ushort Al[128][32];
    __shared__ ushort Bh[64][32];
    __shared__ ushort Bl[64][32];
    const int t = threadIdx.x;
    const int w = t >> 6, l = t & 63;
    const int lr = l & 15, lq = l >> 4;
    // XCD swizzle (512 blocks, 8 XCDs): same m-strip blocks share one XCD's L2
    const int wg = blockIdx.x;
    const int lg = (wg & 7) * 64 + (wg >> 3);
    const int n0 = (lg & 15) * 64;
    const int m0 = (lg >> 4) * 128;
    const int b = m0 >> 10;
    f32x4 acc[2][4] = {};
    for (int k0 = 0; k0 < 512; k0 += 32) {
        __syncthreads();
        #pragma unroll
        for (int u = 0; u < 2; ++u) {
            const int s = (2 * w + u) * 64 + l;
            const int row = s >> 2, pc = (s & 3) << 4;
            const int lc = pc ^ ((row & 3) << 4);
            const size_t src = (size_t)(m0 + row) * 512 + k0 + (lc >> 1);
            gl16(&xh[src], (ushort*)&Ah[0][0] + (2 * w + u) * 512);
            gl16(&xl[src], (ushort*)&Al[0][0] + (2 * w + u) * 512);
        }
        {
            const int s = w * 64 + l;
            const int row = s >> 2, pc = (s & 3) << 4;
            const int lc = pc ^ ((row & 3) << 4);
            const size_t src = (size_t)(n0 + row) * 512 + k0 + (lc >> 1);
            gl16(&wth[src], (ushort*)&Bh[0][0] + w * 512);
            gl16(&wtl[src], (ushort*)&Bl[0][0] + w * 512);
        }
        __syncthreads();
        bf16x8 ah[2], av[2];
        #pragma unroll
        for (int mi = 0; mi < 2; ++mi) {
            const int row = 32 * w + 16 * mi + lr;
            const int sw = (row & 3) << 3;
            ah[mi] = *(const bf16x8*)&Ah[row][(8 * lq) ^ sw];
            av[mi] = *(const bf16x8*)&Al[row][(8 * lq) ^ sw];
        }
        #pragma unroll
        for (int ni = 0; ni < 4; ++ni) {
            const int rowb = 16 * ni + lr;
            const int swb = (rowb & 3) << 3;
            const bf16x8 bh = *(const bf16x8*)&Bh[rowb][(8 * lq) ^ swb];
            const bf16x8 bl = *(const bf16x8*)&Bl[rowb][(8 * lq) ^ swb];
            #pragma unroll
            for (int mi = 0; mi < 2; ++mi) {
                f32x4 a = acc[mi][ni];
                a = __builtin_amdgcn_mfma_f32_16x16x32_bf16(ah[mi], bl, a, 0, 0, 0);
                a = __builtin_amdgcn_mfma_f32_16x16x32_bf16(av[mi], bh, a, 0, 0, 0);
                a = __builtin_amdgcn_mfma_f32_16x16x32_bf16(ah[mi], bh, a, 0, 0, 0);
                acc[mi][ni] = a;
            }
        }
    }
    #pragma unroll
    for (int mi = 0; mi < 2; ++mi)
        #pragma unroll
        for (int ni = 0; ni < 4; ++ni)
            #pragma unroll
            for (int e = 0; e < 4; ++e)
                qkv[(size_t)(m0 + 32 * w + 16 * mi + 4 * lq + e) * 1024 + n0 + 16 * ni + lr] = acc[mi][ni][e];
    #pragma unroll
    for (int ni = 0; ni < 4; ++ni) {
        float s = 0.f, s2 = 0.f;
        #pragma unroll
        for (int mi = 0; mi < 2; ++mi)
            #pragma unroll
            for (int e = 0; e < 4; ++e) { const float v = acc[mi][ni][e]; s += v; s2 += v * v; }
        #pragma unroll
        for (int o = 32; o; o >>= 1) { s += __shfl_xor(s, o, 64); s2 += __shfl_xor(s2, o, 64); }
        if (l == 0) {
            const int g = (n0 + 16 * ni) >> 5;
            atomicAdd(&sumq[(b * 32 + g) * 2 + 0], s);
            atomicAdd(&sumq[(b * 32 + g) * 2 + 1], s2);
        }
    }
}

// ---------------- K2: apply qkv GN (inline finalize) -> bf16 qg + lo (q/k) + transposed v ----------------
__global__ __launch_bounds__(256) void gn_apply_bf(const float* __restrict__ qkv,
                                                   const float* __restrict__ sumq,
                                                   const float* __restrict__ scale,
                                                   const float* __restrict__ bias,
                                                   ushort* __restrict__ qg,
                                                   ushort* __restrict__ qlo,
                                                   ushort* __restrict__ vb) {
    __shared__ float tile[64][65];
    const int b  = blockIdx.z;
    const int l0 = blockIdx.y * 64, c0 = blockIdx.x * 64;
    const int t  = threadIdx.x;
    const bool vhalf = (c0 & 64);
    const int h = c0 >> 7;
    #pragma unroll
    for (int u = 0; u < 16; ++u) {
        const int idx = t + 256 * u;
        const int lr = idx >> 6, cr = idx & 63;
        const int c = c0 + cr, g = c >> 5;
        const float s  = sumq[(b * 32 + g) * 2 + 0];
        const float s2 = sumq[(b * 32 + g) * 2 + 1];
        const float mu = s * (1.f / 32768.f);
        const float rr = rsqrtf(fmaxf(s2 * (1.f / 32768.f) - mu * mu, 0.f) + GEPS);
        float v = qkv[(size_t)(b * LSEQ + l0 + lr) * C2 + c];
        v = (v - mu) * rr * scale[c] + bias[c];
        const ushort hi = f2b(v);
        qg[(size_t)(b * LSEQ + l0 + lr) * C2 + c] = hi;
        if (vhalf) tile[lr][cr] = v;
        else qlo[(size_t)(b * LSEQ + l0 + lr) * 512 + h * 64 + cr] = f2b(v - b2f(hi));
    }
    if (vhalf) {
        __syncthreads();
        #pragma unroll
        for (int u = 0; u < 16; ++u) {
            const int idx = t + 256 * u;
            const int cw = idx >> 6, lw = idx & 63;   // cw = dv
            vb[((size_t)((b * NH + h) * 64 + cw)) * LSEQ + l0 + lw] = f2b(tile[lw][cw]);
        }
    }
}

// ---------------- K3: MFMA flash attention — r7 dataflow + gload_lds staging + XCD swizzle ----------------
// Wave w owns rows [i0+16w, +16). Shared tiles rT/rV/vj staged by gload_lds (linear rows,
// XOR-swizzle ((row&7)<<4) on byte col, applied to BOTH src mapping and reads).
// Wave-private scratch: sA (TUb [0,80) then Ps [0,64), aliased) and sPr. 2 barriers/iter.
__global__ __launch_bounds__(256) void attn_mfma(const ushort* __restrict__ qg,
                                                 const ushort* __restrict__ qlo,
                                                 const ushort* __restrict__ vbuf,
                                                 const ushort* __restrict__ relT,
                                                 const ushort* __restrict__ relV,
                                                 float* __restrict__ aout,
                                                 float* __restrict__ sumo) {
    __shared__ ushort rT[128][64];    // swizzled [rl][d]
    __shared__ ushort rV[64][128];    // swizzled [dv][r-band]
    __shared__ ushort vj[64][64];     // swizzled [dv][jj]
    __shared__ ushort sA[4][16][88];  // per-wave: TUb band, then Ps (aliased)
    __shared__ ushort sPr[4][16][104];// per-wave: skewed P band, zero elsewhere

    const int t = threadIdx.x;
    const int w = t >> 6, l = t & 63;
    const int lr = l & 15, lq = l >> 4;
    // XCD swizzle: 1D grid 512 -> (ib, h, b); the 16 ib's of one (b,h) share an XCD
    const int wg = blockIdx.x;
    const int lg = (wg & 7) * 64 + (wg >> 3);
    const int ib = lg & 15, h = (lg >> 4) & 7, b = lg >> 7;
    const int i0 = ib * 64;
    const int ck0 = w >> 1;

    // A fragments (persistent across j-loop)
    const size_t arow = (size_t)(b * LSEQ + i0 + 16 * w + lr);
    const bf16x8 a_q  = *(const bf16x8*)&qg[arow * C2 + h * 128 + 8 * lq];
    const bf16x8 a_k  = *(const bf16x8*)&qg[arow * C2 + h * 128 + 32 + 8 * lq];
    const bf16x8 a_ql = *(const bf16x8*)&qlo[arow * 512 + h * 64 + 8 * lq];

    {   // zero private Pr band buffer (rewritten band identical each iter; rest stays 0)
        uint* pz = (uint*)&sPr[w][0][0];
        #pragma unroll
        for (int u = 0; u < 13; ++u) pz[l + 64 * u] = 0;
    }

    float m_r[4], l_r[4];
    #pragma unroll
    for (int e = 0; e < 4; ++e) { m_r[e] = -3.0e38f; l_r[e] = 0.f; }
    f32x4 Oa[4] = {};

    const size_t vbase = (size_t)((b * NH + h) * 64) * LSEQ;
    const int tb = 4 * lq + 63 - lr;                          // TU gather base
    const int prbase = 16 * w - 32 * ck0 + 63 + 4 * lq - lr;  // Pr write base

    for (int j0 = 0; j0 < LSEQ; j0 += 64) {
        const int r0 = i0 - j0 + 960;

        // issue-early: this iteration's k hi/lo fragments (consumed after TU)
        bf16x8 kb_hi[4], kb_lo[4];
        #pragma unroll
        for (int n = 0; n < 4; ++n) {
            const size_t krow = (size_t)(b * LSEQ + j0 + 16 * n + lr);
            kb_hi[n] = *(const bf16x8*)&qg[krow * C2 + h * 128 + 32 + 8 * lq];
            kb_lo[n] = *(const bf16x8*)&qlo[krow * 512 + h * 64 + 32 + 8 * lq];
        }

        __syncthreads();   // prior iter's reads of rT/rV/vj complete
        // ---- async staging: rT (16 chunks), rV (16), vj (8); 10 calls/wave ----
        #pragma unroll
        for (int u = 0; u < 4; ++u) {
            const int s = (4 * w + u) * 64 + l;
            const int row = s >> 3, pc = (s & 7) << 4;
            const int lc = pc ^ ((row & 7) << 4);
            gl16(&relT[(size_t)(r0 + row) * 64 + (lc >> 1)], (ushort*)&rT[0][0] + (4 * w + u) * 512);
        }
        #pragma unroll
        for (int u = 0; u < 4; ++u) {
            const int s = (4 * w + u) * 64 + l;
            const int row = s >> 4, pc = (s & 15) << 4;
            const int lc = pc ^ ((row & 7) << 4);
            gl16(&relV[(size_t)row * 2048 + r0 + (lc >> 1)], (ushort*)&rV[0][0] + (4 * w + u) * 512);
        }
        #pragma unroll
        for (int u = 0; u < 2; ++u) {
            const int s = (2 * w + u) * 64 + l;
            const int row = s >> 3, pc = (s & 7) << 4;
            const int lc = pc ^ ((row & 7) << 4);
            gl16(&vbuf[vbase + (size_t)row * LSEQ + j0 + (lc >> 1)], (ushort*)&vj[0][0] + (2 * w + u) * 512);
        }
        __syncthreads();   // staging drained (vmcnt(0) before barrier)

        // ---- TU band: 5 tiles ct = w..w+4 (wave-private from here to loop end) ----
        #pragma unroll
        for (int ct5 = 0; ct5 < 5; ++ct5) {
            const int rr = 16 * (w + ct5) + lr;
            const int sw = (rr & 7) << 3;
            f32x4 acc = {0.f, 0.f, 0.f, 0.f};
            acc = __builtin_amdgcn_mfma_f32_16x16x32_bf16(a_q, *(const bf16x8*)&rT[rr][(8 * lq) ^ sw], acc, 0, 0, 0);
            acc = __builtin_amdgcn_mfma_f32_16x16x32_bf16(a_k, *(const bf16x8*)&rT[rr][(32 + 8 * lq) ^ sw], acc, 0, 0, 0);
            #pragma unroll
            for (int e = 0; e < 4; ++e) sA[w][4 * lq + e][16 * ct5 + lr] = f2b(acc[e]);
        }

        // ---- S1 (compensated bf16, k from hoisted regs) + TU skew-gather ----
        f32x4 sv[4];
        #pragma unroll
        for (int n = 0; n < 4; ++n) {
            f32x4 acc = {0.f, 0.f, 0.f, 0.f};
            acc = __builtin_amdgcn_mfma_f32_16x16x32_bf16(a_q,  kb_lo[n], acc, 0, 0, 0);
            acc = __builtin_amdgcn_mfma_f32_16x16x32_bf16(a_ql, kb_hi[n], acc, 0, 0, 0);
            acc = __builtin_amdgcn_mfma_f32_16x16x32_bf16(a_q,  kb_hi[n], acc, 0, 0, 0);
            #pragma unroll
            for (int e = 0; e < 4; ++e) acc[e] += b2f(sA[w][4 * lq + e][tb + e - 16 * n]);
            sv[n] = acc;
        }

        // ---- in-wave online softmax (rows owned by (lq,e); 16-lane lr reduce) ----
        float mx[4];
        #pragma unroll
        for (int e = 0; e < 4; ++e)
            mx[e] = fmaxf(fmaxf(sv[0][e], sv[1][e]), fmaxf(sv[2][e], sv[3][e]));
        #pragma unroll
        for (int o = 1; o < 16; o <<= 1)
            #pragma unroll
            for (int e = 0; e < 4; ++e) mx[e] = fmaxf(mx[e], __shfl_xor(mx[e], o, 64));
        float alpha[4], ssum[4];
        #pragma unroll
        for (int e = 0; e < 4; ++e) {
            const float mn = fmaxf(m_r[e], mx[e]);
            alpha[e] = __expf(m_r[e] - mn);
            m_r[e] = mn;
            ssum[e] = 0.f;
        }
        #pragma unroll
        for (int n = 0; n < 4; ++n)
            #pragma unroll
            for (int e = 0; e < 4; ++e) {
                const float p = __expf(sv[n][e] - m_r[e]);
                ssum[e] += p;
                const ushort pb = f2b(p);
                sA[w][4 * lq + e][16 * n + lr] = pb;              // Ps (aliased over TUb)
                sPr[w][4 * lq + e][prbase + e - 16 * n] = pb;     // Pr band
            }
        #pragma unroll
        for (int o = 1; o < 16; o <<= 1)
            #pragma unroll
            for (int e = 0; e < 4; ++e) ssum[e] += __shfl_xor(ssum[e], o, 64);
        #pragma unroll
        for (int e = 0; e < 4; ++e) l_r[e] = l_r[e] * alpha[e] + ssum[e];

        // ---- PV: O = diag(alpha)*O + P*v + Pr*rV ----
        const bf16x8 pa0 = *(const bf16x8*)&sA[w][lr][8 * lq];
        const bf16x8 pa1 = *(const bf16x8*)&sA[w][lr][32 + 8 * lq];
        bf16x8 pra[3];
        #pragma unroll
        for (int kk = 0; kk < 3; ++kk) pra[kk] = *(const bf16x8*)&sPr[w][lr][32 * kk + 8 * lq];
        #pragma unroll
        for (int n = 0; n < 4; ++n) {
            const int rw = 16 * n + lr;
            const int sw = (rw & 7) << 3;
            f32x4 acc = Oa[n];
            #pragma unroll
            for (int e = 0; e < 4; ++e) acc[e] *= alpha[e];
            acc = __builtin_amdgcn_mfma_f32_16x16x32_bf16(pa0, *(const bf16x8*)&vj[rw][(8 * lq) ^ sw], acc, 0, 0, 0);
            acc = __builtin_amdgcn_mfma_f32_16x16x32_bf16(pa1, *(const bf16x8*)&vj[rw][(32 + 8 * lq) ^ sw], acc, 0, 0, 0);
            #pragma unroll
            for (int kk = 0; kk < 3; ++kk) {
                acc = __builtin_amdgcn_mfma_f32_16x16x32_bf16(pra[kk],
                        *(const bf16x8*)&rV[rw][(32 * (ck0 + kk) + 8 * lq) ^ sw], acc, 0, 0, 0);
            }
            Oa[n] = acc;
        }
    }

    // ---- epilogue: write O/l + fused out-GN stats ----
    #pragma unroll
    for (int n = 0; n < 4; ++n) {
        float s = 0.f, s2 = 0.f;
        #pragma unroll
        for (int e = 0; e < 4; ++e) {
            const float o = Oa[n][e] / l_r[e];
            aout[((size_t)(b * LSEQ + i0 + 16 * w + 4 * lq + e)) * CIN + h * 64 + 16 * n + lr] = o;
            s += o; s2 += o * o;
        }
        #pragma unroll
        for (int o = 32; o; o >>= 1) { s += __shfl_xor(s, o, 64); s2 += __shfl_xor(s2, o, 64); }
        if (l == 0) {
            atomicAdd(&sumo[(b * 32 + h * 4 + n) * 2 + 0], s);
            atomicAdd(&sumo[(b * 32 + h * 4 + n) * 2 + 1], s2);
        }
    }
}

// ---------------- K4: apply output GN (inline finalize) ----------------
__global__ __launch_bounds__(256) void gn_out_apply(const float* __restrict__ aout,
                                                    const float* __restrict__ sumo,
                                                    const float* __restrict__ scale,
                                                    const float* __restrict__ bias,
                                                    float* __restrict__ out) {
    const int idx4 = blockIdx.x * 256 + threadIdx.x;
    const int c = (idx4 & 127) * 4;
    const size_t row = idx4 >> 7;
    const int b = (int)(row >> 10);
    const int g = c >> 4;
    const float s  = sumo[(b * 32 + g) * 2 + 0];
    const float s2 = sumo[(b * 32 + g) * 2 + 1];
    const float mu = s * (1.f / 16384.f);
    const float rr = rsqrtf(fmaxf(s2 * (1.f / 16384.f) - mu * mu, 0.f) + GEPS);
    const float4 v = *reinterpret_cast<const float4*>(&aout[row * 512 + c]);
    const float4 sc = *reinterpret_cast<const float4*>(&scale[c]);
    const float4 bi = *reinterpret_cast<const float4*>(&bias[c]);
    float4 o;
    o.x = (v.x - mu) * rr * sc.x + bi.x;
    o.y = (v.y - mu) * rr * sc.y + bi.y;
    o.z = (v.z - mu) * rr * sc.z + bi.z;
    o.w = (v.w - mu) * rr * sc.w + bi.w;
    *reinterpret_cast<float4*>(&out[row * 512 + c]) = o;
}

extern "C" void kernel_launch(void* const* d_in, const int* in_sizes, int n_in,
                              void* d_out, int out_size, void* d_ws, size_t ws_size,
                              hipStream_t stream) {
    (void)in_sizes; (void)n_in; (void)out_size; (void)ws_size;
    const float* x   = (const float*)d_in[0];
    const float* W   = (const float*)d_in[1];
    const float* gqs = (const float*)d_in[2];
    const float* gqb = (const float*)d_in[3];
    const float* rel = (const float*)d_in[4];
    const float* gos = (const float*)d_in[5];
    const float* gob = (const float*)d_in[6];
    float* out = (float*)d_out;

    char* ws = (char*)d_ws;
    float*  qkv  = (float*)ws;                                  // 16 MB [b][l][c2] f32
    ushort* qg   = (ushort*)(ws + (16u << 20));                 //  8 MB [b][l][c2] bf16
    ushort* vb   = (ushort*)(ws + (24u << 20));                 //  4 MB [b][h][dv][l]
    ushort* rTb  = (ushort*)(ws + (28u << 20));                 // 256 KB
    ushort* rVb  = (ushort*)(ws + (28u << 20) + (256u << 10));  // 256 KB
    ushort* qlo  = (ushort*)(ws + (28u << 20) + (512u << 10));  //  4 MB [b][l][h*64]
    float*  aout = (float*)ws;                                  // reuse qkv region
    float*  stats = (float*)(ws + (32u << 20) + (512u << 10));  // 2 KB
    float* sumq = stats;          // [b][g][2] raw sums (qkv GN)
    float* sumo = stats + 256;    // [b][g][2] raw sums (out GN)
    // transient (dead after gemm): alias qg/vb regions
    ushort* xhi = (ushort*)(ws + (16u << 20));                  // 4 MB
    ushort* xlo = (ushort*)(ws + (20u << 20));                  // 4 MB
    ushort* wth = (ushort*)(ws + (24u << 20));                  // 1 MB
    ushort* wtl = (ushort*)(ws + (25u << 20));                  // 1 MB

    hipMemsetAsync(stats, 0, 2048, stream);
    prep_all<<<2720, 256, 0, stream>>>(x, W, rel, xhi, xlo, wth, wtl, rTb, rVb);
    gemm_qkv_mfma<<<512, 256, 0, stream>>>(xhi, xlo, wth, wtl, qkv, sumq);
    gn_apply_bf<<<dim3(16, 16, BSZ), 256, 0, stream>>>(qkv, sumq, gqs, gqb, qg, qlo, vb);
    attn_mfma<<<512, 256, 0, stream>>>(qg, qlo, vb, rTb, rVb, aout, sumo);
    gn_out_apply<<<2048, 256, 0, stream>>>(aout, sumo, gos, gob, out);
}